// Round 19
// baseline (159.682 us; speedup 1.0000x reference)
//
#include <hip/hip_runtime.h>
#include <hip/hip_bf16.h>

#define N_ROWS 65536
#define DIM    512
#define BM     64
#define THREADS 1024
#define XB_SZ   65536
#define BBUF_SZ 32768

typedef unsigned short ushort_t;
typedef __bf16 bf16x8 __attribute__((ext_vector_type(8)));
typedef float  f32x4  __attribute__((ext_vector_type(4)));

union BU { uint4 u; bf16x8 b; };
union BFU { __hip_bfloat162 h2; unsigned u; };

// Packed f32x2 -> bf16x2 (RNE) — compiler emits v_cvt_pk_bf16_f32.
__device__ __forceinline__ unsigned pk_bf16(float lo, float hi) {
    BFU z; z.h2 = __float22bfloat162_rn(float2{lo, hi});
    return z.u;
}

__device__ __forceinline__ unsigned f2bf(float f) {
    unsigned u = __float_as_uint(f);
    return (u + 0x7fffu + ((u >> 16) & 1u)) >> 16;   // RNE f32->bf16 (prep only)
}

// Sigmoid-form GELU: x*sigmoid(1.702x). ~5 VALU ops.
__device__ __forceinline__ float gelu_fast(float x) {
    return x * __builtin_amdgcn_rcpf(1.f + __expf(-1.702f * x));
}

// async global->LDS, 16 bytes per lane; lds dest = wave-uniform base + lane*16
__device__ __forceinline__ void gload_lds16(const ushort_t* g, char* l) {
    __builtin_amdgcn_global_load_lds(
        (const __attribute__((address_space(1))) unsigned int*)g,
        (__attribute__((address_space(3))) unsigned int*)l, 16, 0, 0);
}

// Merged prep: z<2 -> transpose + gamma-scale W1/W2 into bf16 [n][k];
// z==2 (y==0 blocks only) -> s1/bb1 column sums.
__global__ void prep_all(const float* __restrict__ W1,
                         const float* __restrict__ W2,
                         const float* __restrict__ gamma,
                         const float* __restrict__ beta,
                         const float* __restrict__ b1,
                         ushort_t* __restrict__ WT,
                         float* __restrict__ s1, float* __restrict__ bb1) {
    __shared__ float tile[32][33];
    const int z = blockIdx.z;
    if (z < 2) {
        const float* W = z ? W2 : W1;
        ushort_t* dst = WT + (size_t)z * DIM * DIM;
        int n0 = blockIdx.x * 32;
        int k0 = blockIdx.y * 32;
        for (int i = threadIdx.y; i < 32; i += 8) {
            float g = z ? 1.f : gamma[k0 + i];
            tile[i][threadIdx.x] = W[(size_t)(k0 + i) * DIM + n0 + threadIdx.x] * g;
        }
        __syncthreads();
        for (int i = threadIdx.y; i < 32; i += 8)
            dst[(size_t)(n0 + i) * DIM + k0 + threadIdx.x] =
                (ushort_t)f2bf(tile[threadIdx.x][i]);
    } else {
        if (blockIdx.y != 0) return;
        float (*red_s)[32] = (float(*)[32])&tile[0][0];   // 8x32
        float (*red_t)[32] = (float(*)[32])&tile[8][0];   // 8x32
        const int cl = threadIdx.x;          // 0..31
        const int kp = threadIdx.y;          // 0..7
        const int c  = blockIdx.x * 32 + cl;
        float s = 0.f, tt = 0.f;
        #pragma unroll 4
        for (int k = kp * 64; k < kp * 64 + 64; ++k) {
            float w = W1[(size_t)k * DIM + c];
            s  += gamma[k] * w;
            tt += beta[k]  * w;
        }
        red_s[kp][cl] = s; red_t[kp][cl] = tt;
        __syncthreads();
        if (kp == 0) {
            float as = 0.f, at = 0.f;
            #pragma unroll
            for (int j = 0; j < 8; ++j) { as += red_s[j][cl]; at += red_t[j][cl]; }
            s1[c]  = as;
            bb1[c] = b1[c] + at;
        }
    }
}

// Fused: stage bf16(x)+stats -> GEMM1(LN-folded,+GELU) -> GEMM2(+bias,+residual)
// R17 frame (best: 151.0us): 16 waves, barrier-free wave-private k-loops,
// 2-deep DMA pipeline, sigmoid-GELU, cvt_pk, setprio.
// R19: unroll-4 k-loops (static ds_read offsets, wider scheduling window).
__global__ __launch_bounds__(THREADS, 4) void fused_mlp(
    const float* __restrict__ x, const ushort_t* __restrict__ W1T,
    const float* __restrict__ s1, const float* __restrict__ bb1,
    const ushort_t* __restrict__ W2T, const float* __restrict__ b2,
    float* __restrict__ out)
{
    __shared__ __align__(16) char smem[XB_SZ + 2 * BBUF_SZ];  // 128 KB: xb | Bbuf0 | Bbuf1
    __shared__ float2 strow[BM];                              // {rstd, -rstd*mu}
    const int t    = threadIdx.x;
    const int wave = t >> 6;             // 0..15
    const int lane = t & 63;
    const int l15  = lane & 15;
    const int kb   = lane >> 4;          // 0..3
    const size_t rowbase = (size_t)blockIdx.x * BM;

    // ---- staging constants: wave stages 2 windows of 16 n-rows each --------
    const int nl = lane >> 2;            // 0..15 (n within window)
    const int sl = lane & 3;             // 16B slot within 64B row
    const int ssw = sl ^ ((nl >> 1) & 3);               // source-chunk permutation
    const unsigned stage_goff = (unsigned)((wave * 32 + nl) * DIM + ssw * 8); // elements
    char* const bwin0 = smem + XB_SZ + wave * 2048;     // + buf*BBUF_SZ; +1024 -> window 1

    // stage W1T slices 0 AND 1 (both buffers) — drained by the P1 barrier
    gload_lds16(W1T + stage_goff, bwin0);
    gload_lds16(W1T + stage_goff + 16 * DIM, bwin0 + 1024);
    gload_lds16(W1T + stage_goff + 32, bwin0 + BBUF_SZ);
    gload_lds16(W1T + stage_goff + 32 + 16 * DIM, bwin0 + BBUF_SZ + 1024);

    // Per-col folded-LN vectors
    float s1v[2], bbv[2];
    #pragma unroll
    for (int n = 0; n < 2; ++n) {
        int c = wave * 32 + n * 16 + l15;
        s1v[n] = s1[c];
        bbv[n] = bb1[c];
    }

    // ---------------- Phase 1: stream x -> bf16 LDS (swizzled) + row stats ---
    {
        const int r   = t >> 4;          // 0..63
        const int sub = t & 15;          // 16 threads/row, 32 cols each
        const float4* xr = (const float4*)(x + (rowbase + r) * DIM) + sub * 8;
        const unsigned swz  = (unsigned)((r & 7) << 4);
        const unsigned base = (unsigned)(r * 1024 + sub * 64);
        const int rot = (sub >> 1) & 3;  // per-lane chunk rotation
        float s = 0.f, ss = 0.f;
        #pragma unroll
        for (int q = 0; q < 4; ++q) {
            const int p = (q + rot) & 3;
            float4 a = xr[2 * p], b = xr[2 * p + 1];
            s  += a.x + a.y + a.z + a.w + b.x + b.y + b.z + b.w;
            ss += a.x*a.x + a.y*a.y + a.z*a.z + a.w*a.w
                + b.x*b.x + b.y*b.y + b.z*b.z + b.w*b.w;
            uint4 pk;
            pk.x = pk_bf16(a.x, a.y);
            pk.y = pk_bf16(a.z, a.w);
            pk.z = pk_bf16(b.x, b.y);
            pk.w = pk_bf16(b.z, b.w);
            *(uint4*)(smem + ((base + (unsigned)(p * 16)) ^ swz)) = pk;
        }
        #pragma unroll
        for (int m = 1; m < 16; m <<= 1) {
            s  += __shfl_xor(s,  m);
            ss += __shfl_xor(ss, m);
        }
        const float mean = s * (1.f / 512.f);
        const float var  = ss * (1.f / 512.f) - mean * mean;
        const float rstd = rsqrtf(var + 1e-5f);
        if (sub == 0) strow[r] = make_float2(rstd, -rstd * mean);
    }
    __syncthreads();   // xb + strow visible; slices 0,1 drained by barrier

    // ---- fragment addressing ----
    const unsigned amask = (unsigned)((l15 & 7) << 4);
    unsigned abase[4];
    #pragma unroll
    for (int m = 0; m < 4; ++m)
        abase[m] = (unsigned)((m * 16 + l15) * 1024 + kb * 16);
    unsigned boff[2];   // B frag read offsets within a Bbuf (swizzled slot)
    #pragma unroll
    for (int n = 0; n < 2; ++n)
        boff[n] = (unsigned)((wave * 32 + n * 16 + l15) * 64 +
                             ((kb ^ ((l15 >> 1) & 3)) * 16));

    f32x4 acc[4][2];

    // ---------------- Phase 2: GEMM1 (LN folded) + GELU -> LDS --------------
    {
        #pragma unroll
        for (int m = 0; m < 4; ++m)
            #pragma unroll
            for (int n = 0; n < 2; ++n)
                acc[m][n] = f32x4{0.f, 0.f, 0.f, 0.f};

        #pragma unroll 4
        for (int ks = 0; ks < 16; ++ks) {
            const int cur = ks & 1;
            if (ks >= 2) {               // slice ks resident; ks+1 may be in flight
                if (ks == 15) { asm volatile("s_waitcnt vmcnt(0)" ::: "memory"); }
                else          { asm volatile("s_waitcnt vmcnt(2)" ::: "memory"); }
                __builtin_amdgcn_sched_barrier(0);
            }
            const char* bb = smem + XB_SZ + cur * BBUF_SZ;
            bf16x8 a[4], b[2];
            #pragma unroll
            for (int n = 0; n < 2; ++n) {
                BU u; u.u = *(const uint4*)(bb + boff[n]);
                b[n] = u.b;
            }
            // B in regs -> buf[cur] free for slice ks+2
            asm volatile("s_waitcnt lgkmcnt(0)" ::: "memory");
            if (ks < 14) {
                const ushort_t* s0 = W1T + stage_goff + (ks + 2) * 32;
                char* l0 = bwin0 + cur * BBUF_SZ;
                gload_lds16(s0, l0);
                gload_lds16(s0 + 16 * DIM, l0 + 1024);
            }
            #pragma unroll
            for (int m = 0; m < 4; ++m) {
                BU u; u.u = *(const uint4*)(smem + ((abase[m] + (unsigned)(ks * 64)) ^ amask));
                a[m] = u.b;
            }
            __builtin_amdgcn_s_setprio(1);
            #pragma unroll
            for (int m = 0; m < 4; ++m)
                #pragma unroll
                for (int n = 0; n < 2; ++n)
                    acc[m][n] = __builtin_amdgcn_mfma_f32_16x16x32_bf16(
                        a[m], b[n], acc[m][n], 0, 0, 0);
            __builtin_amdgcn_s_setprio(0);
        }
        __syncthreads();   // all waves done reading xb

        // stage W2T slices 0,1 — overlap GELU epilogue; drained by next barrier
        gload_lds16(W2T + stage_goff, bwin0);
        gload_lds16(W2T + stage_goff + 16 * DIM, bwin0 + 1024);
        gload_lds16(W2T + stage_goff + 32, bwin0 + BBUF_SZ);
        gload_lds16(W2T + stage_goff + 32 + 16 * DIM, bwin0 + BBUF_SZ + 1024);

        // epilogue: LN scalars + GELU -> overwrite xb with h1 (bf16, swizzled)
        #pragma unroll
        for (int m = 0; m < 4; ++m) {
            const int r0 = m * 16 + kb * 4;
            const float2 sv0 = strow[r0];
            const float2 sv1 = strow[r0 + 1];
            const float2 sv2 = strow[r0 + 2];
            const float2 sv3 = strow[r0 + 3];
            #pragma unroll
            for (int n = 0; n < 2; ++n) {
                const int c = wave * 32 + n * 16 + l15;
                float g0 = gelu_fast(sv0.x * acc[m][n][0] + sv0.y * s1v[n] + bbv[n]);
                float g1 = gelu_fast(sv1.x * acc[m][n][1] + sv1.y * s1v[n] + bbv[n]);
                float g2 = gelu_fast(sv2.x * acc[m][n][2] + sv2.y * s1v[n] + bbv[n]);
                float g3 = gelu_fast(sv3.x * acc[m][n][3] + sv3.y * s1v[n] + bbv[n]);
                unsigned p01 = pk_bf16(g0, g1);
                unsigned p23 = pk_bf16(g2, g3);
                *(ushort_t*)(smem + (unsigned)(((r0    ) * 1024 + c * 2) ^ (((r0    ) & 7) << 4))) = (ushort_t)p01;
                *(ushort_t*)(smem + (unsigned)(((r0 + 1) * 1024 + c * 2) ^ (((r0 + 1) & 7) << 4))) = (ushort_t)(p01 >> 16);
                *(ushort_t*)(smem + (unsigned)(((r0 + 2) * 1024 + c * 2) ^ (((r0 + 2) & 7) << 4))) = (ushort_t)p23;
                *(ushort_t*)(smem + (unsigned)(((r0 + 3) * 1024 + c * 2) ^ (((r0 + 3) & 7) << 4))) = (ushort_t)(p23 >> 16);
            }
        }
    }
    __syncthreads();   // h1 visible; W2T slices 0,1 drained by barrier

    // ---------------- Phase 3: GEMM2 + bias2 + residual -> out (f32) --------
    {
        #pragma unroll
        for (int m = 0; m < 4; ++m)
            #pragma unroll
            for (int n = 0; n < 2; ++n)
                acc[m][n] = f32x4{0.f, 0.f, 0.f, 0.f};

        #pragma unroll 4
        for (int ks = 0; ks < 16; ++ks) {
            const int cur = ks & 1;
            if (ks >= 2) {
                if (ks == 15) { asm volatile("s_waitcnt vmcnt(0)" ::: "memory"); }
                else          { asm volatile("s_waitcnt vmcnt(2)" ::: "memory"); }
                __builtin_amdgcn_sched_barrier(0);
            }
            const char* bb = smem + XB_SZ + cur * BBUF_SZ;
            bf16x8 a[4], b[2];
            #pragma unroll
            for (int n = 0; n < 2; ++n) {
                BU u; u.u = *(const uint4*)(bb + boff[n]);
                b[n] = u.b;
            }
            asm volatile("s_waitcnt lgkmcnt(0)" ::: "memory");
            if (ks < 14) {
                const ushort_t* s0 = W2T + stage_goff + (ks + 2) * 32;
                char* l0 = bwin0 + cur * BBUF_SZ;
                gload_lds16(s0, l0);
                gload_lds16(s0 + 16 * DIM, l0 + 1024);
            }
            #pragma unroll
            for (int m = 0; m < 4; ++m) {
                BU u; u.u = *(const uint4*)(smem + ((abase[m] + (unsigned)(ks * 64)) ^ amask));
                a[m] = u.b;
            }
            __builtin_amdgcn_s_setprio(1);
            #pragma unroll
            for (int m = 0; m < 4; ++m)
                #pragma unroll
                for (int n = 0; n < 2; ++n)
                    acc[m][n] = __builtin_amdgcn_mfma_f32_16x16x32_bf16(
                        a[m], b[n], acc[m][n], 0, 0, 0);
            __builtin_amdgcn_s_setprio(0);
        }
        #pragma unroll
        for (int n = 0; n < 2; ++n) {
            const int c = wave * 32 + n * 16 + l15;
            const float bias = b2[c];
            #pragma unroll
            for (int m = 0; m < 4; ++m) {
                #pragma unroll
                for (int i = 0; i < 4; ++i) {
                    const int r = m * 16 + kb * 4 + i;
                    const size_t gi = (rowbase + (size_t)r) * DIM + (size_t)c;
                    out[gi] = x[gi] + (acc[m][n][i] + bias);
                }
            }
        }
    }
}

extern "C" void kernel_launch(void* const* d_in, const int* in_sizes, int n_in,
                              void* d_out, int out_size, void* d_ws, size_t ws_size,
                              hipStream_t stream) {
    const float* x     = (const float*)d_in[0];
    const float* gamma = (const float*)d_in[1];
    const float* beta  = (const float*)d_in[2];
    const float* W1    = (const float*)d_in[3];
    const float* b1    = (const float*)d_in[4];
    const float* W2    = (const float*)d_in[5];
    const float* b2    = (const float*)d_in[6];
    float* out = (float*)d_out;

    char* ws = (char*)d_ws;
    ushort_t* WT  = (ushort_t*)ws;                       // 1 MB: W1gT | W2T
    float*    s1  = (float*)(ws + 1048576);              // 2 KB
    float*    bb1 = (float*)(ws + 1048576 + 2048);       // 2 KB

    prep_all<<<dim3(DIM / 32, DIM / 32, 3), dim3(32, 8), 0, stream>>>(
        W1, W2, gamma, beta, b1, WT, s1, bb1);
    fused_mlp<<<dim3(N_ROWS / BM), dim3(THREADS), 0, stream>>>(
        x, WT, s1, bb1, WT + DIM * DIM, b2, out);
}

// Round 20
// 151.306 us; speedup vs baseline: 1.0554x; 1.0554x over previous
//
#include <hip/hip_runtime.h>
#include <hip/hip_bf16.h>

#define N_ROWS 65536
#define DIM    512
#define BM     64
#define THREADS 1024
#define XB_SZ   65536
#define BBUF_SZ 32768

typedef unsigned short ushort_t;
typedef __bf16 bf16x8 __attribute__((ext_vector_type(8)));
typedef float  f32x4  __attribute__((ext_vector_type(4)));

union BU { uint4 u; bf16x8 b; };
union BFU { __hip_bfloat162 h2; unsigned u; };

// Packed f32x2 -> bf16x2 (RNE) — compiler emits v_cvt_pk_bf16_f32.
__device__ __forceinline__ unsigned pk_bf16(float lo, float hi) {
    BFU z; z.h2 = __float22bfloat162_rn(float2{lo, hi});
    return z.u;
}

__device__ __forceinline__ unsigned f2bf(float f) {
    unsigned u = __float_as_uint(f);
    return (u + 0x7fffu + ((u >> 16) & 1u)) >> 16;   // RNE f32->bf16 (prep only)
}

// Sigmoid-form GELU: x*sigmoid(1.702x). ~5 VALU ops.
__device__ __forceinline__ float gelu_fast(float x) {
    return x * __builtin_amdgcn_rcpf(1.f + __expf(-1.702f * x));
}

// async global->LDS, 16 bytes per lane; lds dest = wave-uniform base + lane*16
__device__ __forceinline__ void gload_lds16(const ushort_t* g, char* l) {
    __builtin_amdgcn_global_load_lds(
        (const __attribute__((address_space(1))) unsigned int*)g,
        (__attribute__((address_space(3))) unsigned int*)l, 16, 0, 0);
}

// Merged prep: z<2 -> transpose + gamma-scale W1/W2 into bf16 [n][k];
// z==2 (y==0 blocks only) -> s1/bb1 column sums.
__global__ void prep_all(const float* __restrict__ W1,
                         const float* __restrict__ W2,
                         const float* __restrict__ gamma,
                         const float* __restrict__ beta,
                         const float* __restrict__ b1,
                         ushort_t* __restrict__ WT,
                         float* __restrict__ s1, float* __restrict__ bb1) {
    __shared__ float tile[32][33];
    const int z = blockIdx.z;
    if (z < 2) {
        const float* W = z ? W2 : W1;
        ushort_t* dst = WT + (size_t)z * DIM * DIM;
        int n0 = blockIdx.x * 32;
        int k0 = blockIdx.y * 32;
        for (int i = threadIdx.y; i < 32; i += 8) {
            float g = z ? 1.f : gamma[k0 + i];
            tile[i][threadIdx.x] = W[(size_t)(k0 + i) * DIM + n0 + threadIdx.x] * g;
        }
        __syncthreads();
        for (int i = threadIdx.y; i < 32; i += 8)
            dst[(size_t)(n0 + i) * DIM + k0 + threadIdx.x] =
                (ushort_t)f2bf(tile[threadIdx.x][i]);
    } else {
        if (blockIdx.y != 0) return;
        float (*red_s)[32] = (float(*)[32])&tile[0][0];   // 8x32
        float (*red_t)[32] = (float(*)[32])&tile[8][0];   // 8x32
        const int cl = threadIdx.x;          // 0..31
        const int kp = threadIdx.y;          // 0..7
        const int c  = blockIdx.x * 32 + cl;
        float s = 0.f, tt = 0.f;
        #pragma unroll 4
        for (int k = kp * 64; k < kp * 64 + 64; ++k) {
            float w = W1[(size_t)k * DIM + c];
            s  += gamma[k] * w;
            tt += beta[k]  * w;
        }
        red_s[kp][cl] = s; red_t[kp][cl] = tt;
        __syncthreads();
        if (kp == 0) {
            float as = 0.f, at = 0.f;
            #pragma unroll
            for (int j = 0; j < 8; ++j) { as += red_s[j][cl]; at += red_t[j][cl]; }
            s1[c]  = as;
            bb1[c] = b1[c] + at;
        }
    }
}

// Fused: stage bf16(x)+stats -> GEMM1(LN-folded,+GELU) -> GEMM2(+bias,+residual)
// R17 frame (measured best: 151.0us): 16 waves, barrier-free wave-private
// k-loops, 2-deep DMA pipeline (unroll 2), sigmoid-GELU, cvt_pk, setprio.
// R20 = R17 verbatim (R18 8-wave and R19 unroll-4 both regressed).
__global__ __launch_bounds__(THREADS, 4) void fused_mlp(
    const float* __restrict__ x, const ushort_t* __restrict__ W1T,
    const float* __restrict__ s1, const float* __restrict__ bb1,
    const ushort_t* __restrict__ W2T, const float* __restrict__ b2,
    float* __restrict__ out)
{
    __shared__ __align__(16) char smem[XB_SZ + 2 * BBUF_SZ];  // 128 KB: xb | Bbuf0 | Bbuf1
    __shared__ float2 strow[BM];                              // {rstd, -rstd*mu}
    const int t    = threadIdx.x;
    const int wave = t >> 6;             // 0..15
    const int lane = t & 63;
    const int l15  = lane & 15;
    const int kb   = lane >> 4;          // 0..3
    const size_t rowbase = (size_t)blockIdx.x * BM;

    // ---- staging constants: wave stages 2 windows of 16 n-rows each --------
    const int nl = lane >> 2;            // 0..15 (n within window)
    const int sl = lane & 3;             // 16B slot within 64B row
    const int ssw = sl ^ ((nl >> 1) & 3);               // source-chunk permutation
    const unsigned stage_goff = (unsigned)((wave * 32 + nl) * DIM + ssw * 8); // elements
    char* const bwin0 = smem + XB_SZ + wave * 2048;     // + buf*BBUF_SZ; +1024 -> window 1

    // stage W1T slices 0 AND 1 (both buffers) — drained by the P1 barrier
    gload_lds16(W1T + stage_goff, bwin0);
    gload_lds16(W1T + stage_goff + 16 * DIM, bwin0 + 1024);
    gload_lds16(W1T + stage_goff + 32, bwin0 + BBUF_SZ);
    gload_lds16(W1T + stage_goff + 32 + 16 * DIM, bwin0 + BBUF_SZ + 1024);

    // Per-col folded-LN vectors
    float s1v[2], bbv[2];
    #pragma unroll
    for (int n = 0; n < 2; ++n) {
        int c = wave * 32 + n * 16 + l15;
        s1v[n] = s1[c];
        bbv[n] = bb1[c];
    }

    // ---------------- Phase 1: stream x -> bf16 LDS (swizzled) + row stats ---
    {
        const int r   = t >> 4;          // 0..63
        const int sub = t & 15;          // 16 threads/row, 32 cols each
        const float4* xr = (const float4*)(x + (rowbase + r) * DIM) + sub * 8;
        const unsigned swz  = (unsigned)((r & 7) << 4);
        const unsigned base = (unsigned)(r * 1024 + sub * 64);
        const int rot = (sub >> 1) & 3;  // per-lane chunk rotation
        float s = 0.f, ss = 0.f;
        #pragma unroll
        for (int q = 0; q < 4; ++q) {
            const int p = (q + rot) & 3;
            float4 a = xr[2 * p], b = xr[2 * p + 1];
            s  += a.x + a.y + a.z + a.w + b.x + b.y + b.z + b.w;
            ss += a.x*a.x + a.y*a.y + a.z*a.z + a.w*a.w
                + b.x*b.x + b.y*b.y + b.z*b.z + b.w*b.w;
            uint4 pk;
            pk.x = pk_bf16(a.x, a.y);
            pk.y = pk_bf16(a.z, a.w);
            pk.z = pk_bf16(b.x, b.y);
            pk.w = pk_bf16(b.z, b.w);
            *(uint4*)(smem + ((base + (unsigned)(p * 16)) ^ swz)) = pk;
        }
        #pragma unroll
        for (int m = 1; m < 16; m <<= 1) {
            s  += __shfl_xor(s,  m);
            ss += __shfl_xor(ss, m);
        }
        const float mean = s * (1.f / 512.f);
        const float var  = ss * (1.f / 512.f) - mean * mean;
        const float rstd = rsqrtf(var + 1e-5f);
        if (sub == 0) strow[r] = make_float2(rstd, -rstd * mean);
    }
    __syncthreads();   // xb + strow visible; slices 0,1 drained by barrier

    // ---- fragment addressing ----
    const unsigned amask = (unsigned)((l15 & 7) << 4);
    unsigned abase[4];
    #pragma unroll
    for (int m = 0; m < 4; ++m)
        abase[m] = (unsigned)((m * 16 + l15) * 1024 + kb * 16);
    unsigned boff[2];   // B frag read offsets within a Bbuf (swizzled slot)
    #pragma unroll
    for (int n = 0; n < 2; ++n)
        boff[n] = (unsigned)((wave * 32 + n * 16 + l15) * 64 +
                             ((kb ^ ((l15 >> 1) & 3)) * 16));

    f32x4 acc[4][2];

    // ---------------- Phase 2: GEMM1 (LN folded) + GELU -> LDS --------------
    {
        #pragma unroll
        for (int m = 0; m < 4; ++m)
            #pragma unroll
            for (int n = 0; n < 2; ++n)
                acc[m][n] = f32x4{0.f, 0.f, 0.f, 0.f};

        #pragma unroll 2
        for (int ks = 0; ks < 16; ++ks) {
            const int cur = ks & 1;
            if (ks >= 2) {               // slice ks resident; ks+1 may be in flight
                if (ks == 15) { asm volatile("s_waitcnt vmcnt(0)" ::: "memory"); }
                else          { asm volatile("s_waitcnt vmcnt(2)" ::: "memory"); }
                __builtin_amdgcn_sched_barrier(0);
            }
            const char* bb = smem + XB_SZ + cur * BBUF_SZ;
            bf16x8 a[4], b[2];
            #pragma unroll
            for (int n = 0; n < 2; ++n) {
                BU u; u.u = *(const uint4*)(bb + boff[n]);
                b[n] = u.b;
            }
            // B in regs -> buf[cur] free for slice ks+2
            asm volatile("s_waitcnt lgkmcnt(0)" ::: "memory");
            if (ks < 14) {
                const ushort_t* s0 = W1T + stage_goff + (ks + 2) * 32;
                char* l0 = bwin0 + cur * BBUF_SZ;
                gload_lds16(s0, l0);
                gload_lds16(s0 + 16 * DIM, l0 + 1024);
            }
            #pragma unroll
            for (int m = 0; m < 4; ++m) {
                BU u; u.u = *(const uint4*)(smem + ((abase[m] + (unsigned)(ks * 64)) ^ amask));
                a[m] = u.b;
            }
            __builtin_amdgcn_s_setprio(1);
            #pragma unroll
            for (int m = 0; m < 4; ++m)
                #pragma unroll
                for (int n = 0; n < 2; ++n)
                    acc[m][n] = __builtin_amdgcn_mfma_f32_16x16x32_bf16(
                        a[m], b[n], acc[m][n], 0, 0, 0);
            __builtin_amdgcn_s_setprio(0);
        }
        __syncthreads();   // all waves done reading xb

        // stage W2T slices 0,1 — overlap GELU epilogue; drained by next barrier
        gload_lds16(W2T + stage_goff, bwin0);
        gload_lds16(W2T + stage_goff + 16 * DIM, bwin0 + 1024);
        gload_lds16(W2T + stage_goff + 32, bwin0 + BBUF_SZ);
        gload_lds16(W2T + stage_goff + 32 + 16 * DIM, bwin0 + BBUF_SZ + 1024);

        // epilogue: LN scalars + GELU -> overwrite xb with h1 (bf16, swizzled)
        #pragma unroll
        for (int m = 0; m < 4; ++m) {
            const int r0 = m * 16 + kb * 4;
            const float2 sv0 = strow[r0];
            const float2 sv1 = strow[r0 + 1];
            const float2 sv2 = strow[r0 + 2];
            const float2 sv3 = strow[r0 + 3];
            #pragma unroll
            for (int n = 0; n < 2; ++n) {
                const int c = wave * 32 + n * 16 + l15;
                float g0 = gelu_fast(sv0.x * acc[m][n][0] + sv0.y * s1v[n] + bbv[n]);
                float g1 = gelu_fast(sv1.x * acc[m][n][1] + sv1.y * s1v[n] + bbv[n]);
                float g2 = gelu_fast(sv2.x * acc[m][n][2] + sv2.y * s1v[n] + bbv[n]);
                float g3 = gelu_fast(sv3.x * acc[m][n][3] + sv3.y * s1v[n] + bbv[n]);
                unsigned p01 = pk_bf16(g0, g1);
                unsigned p23 = pk_bf16(g2, g3);
                *(ushort_t*)(smem + (unsigned)(((r0    ) * 1024 + c * 2) ^ (((r0    ) & 7) << 4))) = (ushort_t)p01;
                *(ushort_t*)(smem + (unsigned)(((r0 + 1) * 1024 + c * 2) ^ (((r0 + 1) & 7) << 4))) = (ushort_t)(p01 >> 16);
                *(ushort_t*)(smem + (unsigned)(((r0 + 2) * 1024 + c * 2) ^ (((r0 + 2) & 7) << 4))) = (ushort_t)p23;
                *(ushort_t*)(smem + (unsigned)(((r0 + 3) * 1024 + c * 2) ^ (((r0 + 3) & 7) << 4))) = (ushort_t)(p23 >> 16);
            }
        }
    }
    __syncthreads();   // h1 visible; W2T slices 0,1 drained by barrier

    // ---------------- Phase 3: GEMM2 + bias2 + residual -> out (f32) --------
    {
        #pragma unroll
        for (int m = 0; m < 4; ++m)
            #pragma unroll
            for (int n = 0; n < 2; ++n)
                acc[m][n] = f32x4{0.f, 0.f, 0.f, 0.f};

        #pragma unroll 2
        for (int ks = 0; ks < 16; ++ks) {
            const int cur = ks & 1;
            if (ks >= 2) {
                if (ks == 15) { asm volatile("s_waitcnt vmcnt(0)" ::: "memory"); }
                else          { asm volatile("s_waitcnt vmcnt(2)" ::: "memory"); }
                __builtin_amdgcn_sched_barrier(0);
            }
            const char* bb = smem + XB_SZ + cur * BBUF_SZ;
            bf16x8 a[4], b[2];
            #pragma unroll
            for (int n = 0; n < 2; ++n) {
                BU u; u.u = *(const uint4*)(bb + boff[n]);
                b[n] = u.b;
            }
            asm volatile("s_waitcnt lgkmcnt(0)" ::: "memory");
            if (ks < 14) {
                const ushort_t* s0 = W2T + stage_goff + (ks + 2) * 32;
                char* l0 = bwin0 + cur * BBUF_SZ;
                gload_lds16(s0, l0);
                gload_lds16(s0 + 16 * DIM, l0 + 1024);
            }
            #pragma unroll
            for (int m = 0; m < 4; ++m) {
                BU u; u.u = *(const uint4*)(smem + ((abase[m] + (unsigned)(ks * 64)) ^ amask));
                a[m] = u.b;
            }
            __builtin_amdgcn_s_setprio(1);
            #pragma unroll
            for (int m = 0; m < 4; ++m)
                #pragma unroll
                for (int n = 0; n < 2; ++n)
                    acc[m][n] = __builtin_amdgcn_mfma_f32_16x16x32_bf16(
                        a[m], b[n], acc[m][n], 0, 0, 0);
            __builtin_amdgcn_s_setprio(0);
        }
        #pragma unroll
        for (int n = 0; n < 2; ++n) {
            const int c = wave * 32 + n * 16 + l15;
            const float bias = b2[c];
            #pragma unroll
            for (int m = 0; m < 4; ++m) {
                #pragma unroll
                for (int i = 0; i < 4; ++i) {
                    const int r = m * 16 + kb * 4 + i;
                    const size_t gi = (rowbase + (size_t)r) * DIM + (size_t)c;
                    out[gi] = x[gi] + (acc[m][n][i] + bias);
                }
            }
        }
    }
}

extern "C" void kernel_launch(void* const* d_in, const int* in_sizes, int n_in,
                              void* d_out, int out_size, void* d_ws, size_t ws_size,
                              hipStream_t stream) {
    const float* x     = (const float*)d_in[0];
    const float* gamma = (const float*)d_in[1];
    const float* beta  = (const float*)d_in[2];
    const float* W1    = (const float*)d_in[3];
    const float* b1    = (const float*)d_in[4];
    const float* W2    = (const float*)d_in[5];
    const float* b2    = (const float*)d_in[6];
    float* out = (float*)d_out;

    char* ws = (char*)d_ws;
    ushort_t* WT  = (ushort_t*)ws;                       // 1 MB: W1gT | W2T
    float*    s1  = (float*)(ws + 1048576);              // 2 KB
    float*    bb1 = (float*)(ws + 1048576 + 2048);       // 2 KB

    prep_all<<<dim3(DIM / 32, DIM / 32, 3), dim3(32, 8), 0, stream>>>(
        W1, W2, gamma, beta, b1, WT, s1, bb1);
    fused_mlp<<<dim3(N_ROWS / BM), dim3(THREADS), 0, stream>>>(
        x, WT, s1, bb1, WT + DIM * DIM, b2, out);
}